// Round 6
// baseline (301.712 us; speedup 1.0000x reference)
//
#include <hip/hip_runtime.h>
#include <hip/hip_bf16.h>

typedef __attribute__((ext_vector_type(8))) short bf16x8;
typedef __attribute__((ext_vector_type(4))) float f32x4;
typedef unsigned short u16;

#define RMS_EPS 1.1920929e-07f

constexpr int Bb = 2, Ss = 2048, DM = 2048, NH = 16;
constexpr int MROWS = Bb * Ss; // 4096

__device__ __forceinline__ u16 f2bf(float f) {
    __hip_bfloat16 h = __float2bfloat16(f);
    return *reinterpret_cast<u16*>(&h);
}

__device__ __forceinline__ float exp2_fast(float x) {
    float r; asm("v_exp_f32 %0, %1" : "=v"(r) : "v"(x)); return r;
}

__device__ __forceinline__ void gload16(const void* g, void* l) {
    __builtin_amdgcn_global_load_lds(
        (const __attribute__((address_space(1))) unsigned int*)g,
        (__attribute__((address_space(3))) unsigned int*)l, 16, 0, 0);
}

// ---------------- merged fp32 -> bf16 convert (7 segments, sizes fixed) -------
__global__ __launch_bounds__(256) void cvt_all(
    const float* __restrict__ s0, u16* __restrict__ d0,
    const float* __restrict__ s1, u16* __restrict__ d1,
    const float* __restrict__ s2, u16* __restrict__ d2,
    const float* __restrict__ s3, u16* __restrict__ d3,
    const float* __restrict__ s4, u16* __restrict__ d4,
    const float* __restrict__ s5, u16* __restrict__ d5,
    const float* __restrict__ s6, u16* __restrict__ d6)
{
    int i = blockIdx.x * 256 + threadIdx.x;   // float4 index; grid covers exactly 5373952
    const float* s; u16* d; int off;
    if (i < 2097152)      { s = s0; d = d0; off = 0; }
    else if (i < 2621440) { s = s1; d = d1; off = 2097152; }
    else if (i < 2883584) { s = s2; d = d2; off = 2621440; }
    else if (i < 3407872) { s = s3; d = d3; off = 2883584; }
    else if (i < 3932160) { s = s4; d = d4; off = 3407872; }
    else if (i < 4325376) { s = s5; d = d5; off = 3932160; }
    else                  { s = s6; d = d6; off = 4325376; }
    int j = i - off;
    float4 v = reinterpret_cast<const float4*>(s)[j];
    ushort4 o;
    o.x = f2bf(v.x); o.y = f2bf(v.y); o.z = f2bf(v.z); o.w = f2bf(v.w);
    reinterpret_cast<ushort4*>(d)[j] = o;
}

__global__ void build_bcat(const float* __restrict__ qb, const float* __restrict__ kvb,
                           const float* __restrict__ krb, float* __restrict__ bcat) {
    int i = blockIdx.x * 256 + threadIdx.x;
    if (i < 1024) bcat[i] = qb[i];
    else if (i < 1536) bcat[i] = kvb[i - 1024];
    else if (i < 2560) bcat[i] = krb[i - 1536];
}

// ---------------- GEMM: C(M,N) = A(M,K) * Bt(N,K)^T + bias ----------------
template <typename OutT>
__global__ __launch_bounds__(256) void gemm_bt(
    const u16* __restrict__ A, const u16* __restrict__ Bt,
    const float* __restrict__ bias, OutT* __restrict__ C,
    int M, int N, int K)
{
    __shared__ alignas(16) u16 sA[128 * 32];
    __shared__ alignas(16) u16 sB[128 * 32];
    const int tid = threadIdx.x;
    const int lane = tid & 63;
    const int w = tid >> 6;
    const int wr = w >> 1, wc = w & 1;
    const int l16 = lane & 15, lq = lane >> 4;
    const int tileM = blockIdx.y * 128;
    const int tileN = blockIdx.x * 128;

    f32x4 acc[4][4];
#pragma unroll
    for (int m = 0; m < 4; m++)
#pragma unroll
        for (int n = 0; n < 4; n++)
#pragma unroll
            for (int r = 0; r < 4; r++) acc[m][n][r] = 0.f;

    const int srow = w * 16 + (lane >> 2);
    const int scol = (lane & 3) * 8;
    const u16* gA0 = A + (size_t)(tileM + srow) * K + scol;
    const u16* gA1 = A + (size_t)(tileM + srow + 64) * K + scol;
    const u16* gB0 = Bt + (size_t)(tileN + srow) * K + scol;
    const u16* gB1 = Bt + (size_t)(tileN + srow + 64) * K + scol;
    u16* lA0 = sA + w * 512;
    u16* lA1 = sA + 2048 + w * 512;
    u16* lB0 = sB + w * 512;
    u16* lB1 = sB + 2048 + w * 512;

    int aoff[4], boff[4];
#pragma unroll
    for (int m = 0; m < 4; m++) aoff[m] = (wr * 64 + m * 16 + l16) * 32 + lq * 8;
#pragma unroll
    for (int n = 0; n < 4; n++) boff[n] = (wc * 64 + n * 16 + l16) * 32 + lq * 8;

    const int nk = K >> 5;
    for (int kk = 0; kk < nk; ++kk) {
        __syncthreads();
        gload16(gA0, lA0);
        gload16(gA1, lA1);
        gload16(gB0, lB0);
        gload16(gB1, lB1);
        gA0 += 32; gA1 += 32; gB0 += 32; gB1 += 32;
        __syncthreads();
        bf16x8 af[4], bfr[4];
#pragma unroll
        for (int m = 0; m < 4; m++) af[m] = *(const bf16x8*)&sA[aoff[m]];
#pragma unroll
        for (int n = 0; n < 4; n++) bfr[n] = *(const bf16x8*)&sB[boff[n]];
        __builtin_amdgcn_s_setprio(1);
#pragma unroll
        for (int m = 0; m < 4; m++)
#pragma unroll
            for (int n = 0; n < 4; n++)
                acc[m][n] = __builtin_amdgcn_mfma_f32_16x16x32_bf16(af[m], bfr[n], acc[m][n], 0, 0, 0);
        __builtin_amdgcn_s_setprio(0);
    }

#pragma unroll
    for (int n = 0; n < 4; n++) {
        int col = tileN + wc * 64 + n * 16 + l16;
        float bv = bias ? bias[col] : 0.f;
#pragma unroll
        for (int m = 0; m < 4; m++) {
            int rowb = tileM + wr * 64 + m * 16 + (lq << 2);
#pragma unroll
            for (int r = 0; r < 4; r++) {
                float v = acc[m][n][r] + bv;
                if constexpr (sizeof(OutT) == 2)
                    C[(size_t)(rowb + r) * N + col] = (OutT)f2bf(v);
                else
                    C[(size_t)(rowb + r) * N + col] = (OutT)v;
            }
        }
    }
}

// ---------------- fused down-proj GEMM: N=2560 (1024 q | 512 kv | 1024 rope) ----
__global__ __launch_bounds__(256) void gemm_down(
    const u16* __restrict__ A, const u16* __restrict__ Bt,
    const float* __restrict__ bcat, float* __restrict__ dcat,
    u16* __restrict__ krbuf)
{
    constexpr int K = 2048;
    __shared__ alignas(16) u16 sA[128 * 32];
    __shared__ alignas(16) u16 sB[128 * 32];
    const int tid = threadIdx.x;
    const int lane = tid & 63;
    const int w = tid >> 6;
    const int wr = w >> 1, wc = w & 1;
    const int l16 = lane & 15, lq = lane >> 4;
    const int tileM = blockIdx.y * 128;
    const int tileN = blockIdx.x * 128;

    f32x4 acc[4][4];
#pragma unroll
    for (int m = 0; m < 4; m++)
#pragma unroll
        for (int n = 0; n < 4; n++)
#pragma unroll
            for (int r = 0; r < 4; r++) acc[m][n][r] = 0.f;

    const int srow = w * 16 + (lane >> 2);
    const int scol = (lane & 3) * 8;
    const u16* gA0 = A + (size_t)(tileM + srow) * K + scol;
    const u16* gA1 = A + (size_t)(tileM + srow + 64) * K + scol;
    const u16* gB0 = Bt + (size_t)(tileN + srow) * K + scol;
    const u16* gB1 = Bt + (size_t)(tileN + srow + 64) * K + scol;
    u16* lA0 = sA + w * 512;
    u16* lA1 = sA + 2048 + w * 512;
    u16* lB0 = sB + w * 512;
    u16* lB1 = sB + 2048 + w * 512;

    int aoff[4], boff[4];
#pragma unroll
    for (int m = 0; m < 4; m++) aoff[m] = (wr * 64 + m * 16 + l16) * 32 + lq * 8;
#pragma unroll
    for (int n = 0; n < 4; n++) boff[n] = (wc * 64 + n * 16 + l16) * 32 + lq * 8;

    const int nk = K >> 5;
    for (int kk = 0; kk < nk; ++kk) {
        __syncthreads();
        gload16(gA0, lA0);
        gload16(gA1, lA1);
        gload16(gB0, lB0);
        gload16(gB1, lB1);
        gA0 += 32; gA1 += 32; gB0 += 32; gB1 += 32;
        __syncthreads();
        bf16x8 af[4], bfr[4];
#pragma unroll
        for (int m = 0; m < 4; m++) af[m] = *(const bf16x8*)&sA[aoff[m]];
#pragma unroll
        for (int n = 0; n < 4; n++) bfr[n] = *(const bf16x8*)&sB[boff[n]];
        __builtin_amdgcn_s_setprio(1);
#pragma unroll
        for (int m = 0; m < 4; m++)
#pragma unroll
            for (int n = 0; n < 4; n++)
                acc[m][n] = __builtin_amdgcn_mfma_f32_16x16x32_bf16(af[m], bfr[n], acc[m][n], 0, 0, 0);
        __builtin_amdgcn_s_setprio(0);
    }

    const bool isrope = (tileN >= 1536);
#pragma unroll
    for (int n = 0; n < 4; n++) {
        int col = tileN + wc * 64 + n * 16 + l16;
        float bv = bcat[col];
#pragma unroll
        for (int m = 0; m < 4; m++) {
            int rowb = tileM + wr * 64 + m * 16 + (lq << 2);
#pragma unroll
            for (int r = 0; r < 4; r++) {
                float v = acc[m][n][r] + bv;
                if (!isrope) dcat[(size_t)(rowb + r) * 1536 + col] = v;
                else         krbuf[(size_t)(rowb + r) * 1024 + (col - 1536)] = f2bf(v);
            }
        }
    }
}

// ---------------- RMS norm (row-wise, strided in), fp32 in -> bf16 out --------
template <int C>
__global__ __launch_bounds__(256) void rmsnorm_bf16(
    const float* __restrict__ in, int istride, const float* __restrict__ wgt, u16* __restrict__ out)
{
    const int row = blockIdx.x;
    const int tid = threadIdx.x;
    constexpr int PER = C / 256;
    const float* p = in + (size_t)row * istride;
    float v[PER];
    float ss = 0.f;
#pragma unroll
    for (int i = 0; i < PER; i++) { v[i] = p[tid + i * 256]; ss += v[i] * v[i]; }
#pragma unroll
    for (int o = 32; o; o >>= 1) ss += __shfl_xor(ss, o, 64);
    __shared__ float red[4];
    if ((tid & 63) == 0) red[tid >> 6] = ss;
    __syncthreads();
    float tot = red[0] + red[1] + red[2] + red[3];
    float inv = rsqrtf(tot / (float)C + RMS_EPS);
    u16* q = out + (size_t)row * C;
#pragma unroll
    for (int i = 0; i < PER; i++) {
        int c = tid + i * 256;
        q[c] = f2bf(v[i] * inv * wgt[c]);
    }
}

// ---------------- V transpose: kvbuf[token][h*192+64+d] -> vT[(h*128+d)*4096+token]
__global__ __launch_bounds__(256) void transpose_v(
    const u16* __restrict__ kvbuf, u16* __restrict__ vT)
{
    __shared__ alignas(16) u16 tile[64][72];
    const int tid = threadIdx.x;
    const int t0 = blockIdx.x * 64;
    const int h = blockIdx.y >> 1, dh = blockIdx.y & 1;
    const int trow = tid >> 2, c8 = (tid & 3) * 8;
    const u16* src = kvbuf + (size_t)(t0 + trow) * 3072 + h * 192 + 64 + dh * 64 + c8;
    *(bf16x8*)&tile[trow][c8]      = *(const bf16x8*)src;
    *(bf16x8*)&tile[trow][c8 + 32] = *(const bf16x8*)(src + 32);
    __syncthreads();
    const int drow = tid >> 2, tc8 = (tid & 3) * 8;
    bf16x8 a, b2;
#pragma unroll
    for (int j = 0; j < 8; j++) {
        a[j]  = (short)tile[tc8 + j][drow];
        b2[j] = (short)tile[tc8 + 32 + j][drow];
    }
    u16* dst = vT + (size_t)(h * 128 + dh * 64 + drow) * MROWS + t0 + tc8;
    *(bf16x8*)dst = a;
    *(bf16x8*)(dst + 32) = b2;
}

// ---------------- causal flash attention, K-split into 512 uniform blocks ----
// QBLK=128 (4 waves x 32 q), KT=64. Pair p of q-tiles {p, 15-p}:
//  half0 block: all of qt=p (2p+2 tiles, masked, FINAL) + qt=15-p tiles [0,15-2p) (PART0)
//  half1 block: qt=15-p tiles [15-2p, 32-2p) (masked, PART1)
// Every block = exactly 17 k-tiles. 512 blocks -> 2 blocks/CU (co-resident
// blocks are the two halves of the same (bh,p): same K/V range in L2).
__global__ __launch_bounds__(256) void mla_attn(
    const u16* __restrict__ qbuf,   // (4096, 2048) head-major h*128
    const u16* __restrict__ kvbuf,  // (4096, 3072) per head 192: knope(64) v(128)
    const u16* __restrict__ krbuf,  // (4096, 1024) per head 64
    const u16* __restrict__ vT,     // (h*128+d, 4096 tokens)
    u16* __restrict__ obuf,         // (4096, 2048) final attention out
    float* __restrict__ part0,      // [256][128][128] f32 unnormalized O, half0
    float* __restrict__ p1a,        // half1 partials, pi < 192
    float* __restrict__ p1b,        // half1 partials, pi >= 192
    float* __restrict__ ml)         // [256][2][128] float2 (m, l)
{
    const int flat = blockIdx.x + 16 * blockIdx.y;
    const int cu_slot = flat & 255;
    const int half = flat >> 8;
    const int xcd = cu_slot & 7, ii = cu_slot >> 3;
    const int bh = xcd * 4 + (ii >> 3);      // 4 consecutive bh per XCD
    const int p  = ii & 7;
    const int b = bh >> 4, h = bh & 15;
    const int pi = bh * 8 + p;
    const int tid = threadIdx.x, lane = tid & 63, w = tid >> 6;
    const int l16 = lane & 15, lq = lane >> 4;

    __shared__ alignas(16) u16 sK[64 * 128];
    __shared__ alignas(16) u16 sVt[128 * 64];
    __shared__ alignas(16) u16 sP[8][16 * 64];   // [w*2+g][q16][k64], swizzled

    const int rowbase = b * Ss;
    const int sr = tid >> 2, sc = (tid & 3) * 32;   // K staging
    const int vd = tid >> 1, vh = (tid & 1) * 32;   // V staging
    const float C1 = 0.12751742f;    // softmax_scale * log2(e)
    const float THRR = 90.5f;        // defer-max threshold (raw units)

    const int nseg = half ? 1 : 2;
#pragma unroll 1
    for (int s = 0; s < nseg; ++s) {
        int qt, k0, k1, mode;   // mode: 0=final, 1=part0, 2=part1
        bool domask;
        if (half == 0) {
            if (s == 0) { qt = p;      k0 = 0;          k1 = 2 * p + 2;  domask = true;  mode = 0; }
            else        { qt = 15 - p; k0 = 0;          k1 = 15 - 2 * p; domask = false; mode = 1; }
        } else          { qt = 15 - p; k0 = 15 - 2 * p; k1 = 32 - 2 * p; domask = true;  mode = 2; }
        const int q0 = qt * 128;

        bf16x8 qf[2][4];
#pragma unroll
        for (int g = 0; g < 2; ++g) {
            const u16* qp = qbuf + (size_t)(rowbase + q0 + w * 32 + g * 16 + l16) * 2048 + h * 128 + lq * 8;
#pragma unroll
            for (int c = 0; c < 4; c++) qf[g][c] = *(const bf16x8*)(qp + c * 32);
        }
        float mi[2], li[2];
        f32x4 o[2][8];
#pragma unroll
        for (int g = 0; g < 2; ++g) {
            mi[g] = -3e38f; li[g] = 0.f;
#pragma unroll
            for (int d = 0; d < 8; d++)
#pragma unroll
                for (int r = 0; r < 4; r++) o[g][d][r] = 0.f;
        }

        bf16x8 kr[4], vr[4];
        {   // prologue: tile k0 -> regs
            const int krow = rowbase + k0 * 64 + sr;
            const u16* src = (sc < 64)
                ? kvbuf + (size_t)krow * 3072 + h * 192 + sc
                : krbuf + (size_t)krow * 1024 + h * 64 + (sc - 64);
#pragma unroll
            for (int j = 0; j < 4; j++) kr[j] = *(const bf16x8*)(src + j * 8);
            const u16* vsrc = vT + (size_t)(h * 128 + vd) * MROWS + rowbase + k0 * 64 + vh;
#pragma unroll
            for (int j = 0; j < 4; j++) vr[j] = *(const bf16x8*)(vsrc + j * 8);
        }

#pragma unroll 1
        for (int kt = k0; kt < k1; ++kt) {
            __syncthreads();
#pragma unroll
            for (int j = 0; j < 4; j++) {
                int byteoff = sr * 256 + (sc + j * 8) * 2;
                *(bf16x8*)((char*)sK + (byteoff ^ ((sr & 7) << 4))) = kr[j];
            }
#pragma unroll
            for (int j = 0; j < 4; j++) {
                int byteoff = vd * 128 + (vh + j * 8) * 2;
                *(bf16x8*)((char*)sVt + (byteoff ^ ((vd & 7) << 4))) = vr[j];
            }
            __syncthreads();
            if (kt + 1 < k1) {   // prefetch next tile into regs (hides under compute)
                const int krow = rowbase + (kt + 1) * 64 + sr;
                const u16* src = (sc < 64)
                    ? kvbuf + (size_t)krow * 3072 + h * 192 + sc
                    : krbuf + (size_t)krow * 1024 + h * 64 + (sc - 64);
#pragma unroll
                for (int j = 0; j < 4; j++) kr[j] = *(const bf16x8*)(src + j * 8);
                const u16* vsrc = vT + (size_t)(h * 128 + vd) * MROWS + rowbase + (kt + 1) * 64 + vh;
#pragma unroll
                for (int j = 0; j < 4; j++) vr[j] = *(const bf16x8*)(vsrc + j * 8);
            }

            // wave-dead skip (only possible in masked segments)
            const bool alive = !domask || (kt * 64) <= (q0 + w * 32 + 15);
            if (alive) {
                f32x4 scf[2][4];
#pragma unroll
                for (int g = 0; g < 2; ++g)
#pragma unroll
                    for (int n = 0; n < 4; n++)
#pragma unroll
                        for (int r = 0; r < 4; r++) scf[g][n][r] = 0.f;
                __builtin_amdgcn_s_setprio(1);
#pragma unroll
                for (int n = 0; n < 4; n++) {
#pragma unroll
                    for (int c = 0; c < 4; c++) {
                        int row = n * 16 + l16;
                        int byteoff = row * 256 + (c * 32 + lq * 8) * 2;
                        bf16x8 kf = *(const bf16x8*)((char*)sK + (byteoff ^ ((row & 7) << 4)));
                        scf[0][n] = __builtin_amdgcn_mfma_f32_16x16x32_bf16(kf, qf[0][c], scf[0][n], 0, 0, 0);
                        scf[1][n] = __builtin_amdgcn_mfma_f32_16x16x32_bf16(kf, qf[1][c], scf[1][n], 0, 0, 0);
                    }
                }
                __builtin_amdgcn_s_setprio(0);

#pragma unroll
                for (int g = 0; g < 2; ++g) {
                    const int base = q0 + w * 32 + g * 16;
                    if (domask && (kt * 64 + 63 > base)) {   // diagonal-adjacent only
                        const int qg = base + l16;
#pragma unroll
                        for (int n = 0; n < 4; n++)
#pragma unroll
                            for (int r = 0; r < 4; r++) {
                                int kg = kt * 64 + n * 16 + lq * 4 + r;
                                if (kg > qg) scf[g][n][r] = -3e38f;
                            }
                    }
                    float mx = mi[g];
#pragma unroll
                    for (int n = 0; n < 4; n++)
#pragma unroll
                        for (int r = 0; r < 4; r++) mx = fmaxf(mx, scf[g][n][r]);
                    mx = fmaxf(mx, __shfl_xor(mx, 16, 64));
                    mx = fmaxf(mx, __shfl_xor(mx, 32, 64));
                    if (!__all(mx - mi[g] <= THRR)) {   // T13 defer-max
                        float f = exp2_fast((mi[g] - mx) * C1);
                        li[g] *= f;
#pragma unroll
                        for (int d = 0; d < 8; d++)
#pragma unroll
                            for (int r = 0; r < 4; r++) o[g][d][r] *= f;
                        mi[g] = mx;
                    }
                    float mc = mi[g] * C1;
                    float rs = 0.f;
#pragma unroll
                    for (int n = 0; n < 4; n++)
#pragma unroll
                        for (int r = 0; r < 4; r++) {
                            float pv = exp2_fast(__fmaf_rn(scf[g][n][r], C1, -mc));
                            scf[g][n][r] = pv;
                            rs += pv;
                        }
                    rs += __shfl_xor(rs, 16, 64);
                    rs += __shfl_xor(rs, 32, 64);
                    li[g] += rs;
                    char* pb = (char*)sP + ((w << 1) | g) * 2048;
#pragma unroll
                    for (int n = 0; n < 4; n++) {
                        ushort4 pk;
                        pk.x = f2bf(scf[g][n][0]); pk.y = f2bf(scf[g][n][1]);
                        pk.z = f2bf(scf[g][n][2]); pk.w = f2bf(scf[g][n][3]);
                        int byteoff = l16 * 128 + n * 32 + lq * 8;
                        *(ushort4*)(pb + (byteoff ^ ((l16 & 7) << 4))) = pk;
                    }
                }

                __builtin_amdgcn_s_setprio(1);
#pragma unroll
                for (int c = 0; c < 2; c++) {
                    bf16x8 pf[2];
#pragma unroll
                    for (int g = 0; g < 2; ++g) {
                        char* pb = (char*)sP + ((w << 1) | g) * 2048;
                        int pbyte = l16 * 128 + (c * 32 + lq * 8) * 2;
                        pf[g] = *(const bf16x8*)(pb + (pbyte ^ ((l16 & 7) << 4)));
                    }
#pragma unroll
                    for (int d = 0; d < 8; d++) {
                        int vrow = d * 16 + l16;
                        int vbyte = vrow * 128 + (c * 32 + lq * 8) * 2;
                        bf16x8 vf = *(const bf16x8*)((char*)sVt + (vbyte ^ ((vrow & 7) << 4)));
                        o[0][d] = __builtin_amdgcn_mfma_f32_16x16x32_bf16(vf, pf[0], o[0][d], 0, 0, 0);
                        o[1][d] = __builtin_amdgcn_mfma_f32_16x16x32_bf16(vf, pf[1], o[1][d], 0, 0, 0);
                    }
                }
                __builtin_amdgcn_s_setprio(0);
            }
        }

        if (mode == 0) {
            // final write: lane holds O^T[d][q=l16] per group
#pragma unroll
            for (int g = 0; g < 2; ++g) {
                float invl = 1.f / li[g];
                u16* op = obuf + (size_t)(rowbase + q0 + w * 32 + g * 16 + l16) * 2048 + h * 128;
#pragma unroll
                for (int d = 0; d < 8; d++) {
                    ushort4 ok;
                    ok.x = f2bf(o[g][d][0] * invl); ok.y = f2bf(o[g][d][1] * invl);
                    ok.z = f2bf(o[g][d][2] * invl); ok.w = f2bf(o[g][d][3] * invl);
                    *(ushort4*)(op + d * 16 + lq * 4) = ok;
                }
            }
        } else {
            float* PB = (mode == 1)
                ? part0 + (size_t)pi * 16384
                : (pi < 192 ? p1a + (size_t)pi * 16384 : p1b + (size_t)(pi - 192) * 16384);
            const int hslot = (mode == 2) ? 1 : 0;
#pragma unroll
            for (int g = 0; g < 2; ++g) {
                const int rloc = w * 32 + g * 16 + l16;
#pragma unroll
                for (int d = 0; d < 8; d++)
                    *(f32x4*)(PB + rloc * 128 + d * 16 + lq * 4) = o[g][d];
                if (lq == 0) {
                    float2 v; v.x = mi[g]; v.y = li[g];
                    *(float2*)(ml + ((size_t)(pi * 2 + hslot) * 128 + rloc) * 2) = v;
                }
            }
        }
    }
}

// ---------------- merge of the two K-split partials (qt_large rows) ----------
__global__ __launch_bounds__(256) void attn_merge(
    const float* __restrict__ part0, const float* __restrict__ p1a,
    const float* __restrict__ p1b, const float* __restrict__ ml,
    u16* __restrict__ obuf)
{
    const int pi = blockIdx.y;            // [0,256)
    const int quarter = blockIdx.x;       // [0,4)
    const int t = threadIdx.x;
    const int r = quarter * 32 + (t >> 3);
    const int d0 = (t & 7) * 16;
    const int bh = pi >> 3, p = pi & 7, qt = 15 - p;
    const int b = bh >> 4, h = bh & 15;
    const float C1 = 0.12751742f;
    float2 ml0 = *(const float2*)(ml + ((size_t)(pi * 2 + 0) * 128 + r) * 2);
    float2 ml1 = *(const float2*)(ml + ((size_t)(pi * 2 + 1) * 128 + r) * 2);
    float m = fmaxf(ml0.x, ml1.x);
    float a0 = exp2_fast((ml0.x - m) * C1);
    float a1 = exp2_fast((ml1.x - m) * C1);
    float inv = 1.f / (ml0.y * a0 + ml1.y * a1);
    const float* P0 = part0 + (size_t)pi * 16384 + r * 128 + d0;
    const float* P1 = (pi < 192 ? p1a + (size_t)pi * 16384 : p1b + (size_t)(pi - 192) * 16384) + r * 128 + d0;
    u16* dst = obuf + (size_t)(b * Ss + qt * 128 + r) * 2048 + h * 128 + d0;
#pragma unroll
    for (int j = 0; j < 4; j++) {
        float4 o0 = *(const float4*)(P0 + j * 4);
        float4 o1 = *(const float4*)(P1 + j * 4);
        ushort4 ov;
        ov.x = f2bf((o0.x * a0 + o1.x * a1) * inv);
        ov.y = f2bf((o0.y * a0 + o1.y * a1) * inv);
        ov.z = f2bf((o0.z * a0 + o1.z * a1) * inv);
        ov.w = f2bf((o0.w * a0 + o1.w * a1) * inv);
        *(ushort4*)(dst + j * 4) = ov;
    }
}

// ---------------- launch ----------------
extern "C" void kernel_launch(void* const* d_in, const int* in_sizes, int n_in,
                              void* d_out, int out_size, void* d_ws, size_t ws_size,
                              hipStream_t stream) {
    const float* x        = (const float*)d_in[0];
    const float* q_down_w = (const float*)d_in[1];
    const float* q_down_b = (const float*)d_in[2];
    const float* q_norm_w = (const float*)d_in[3];
    const float* q_up_w   = (const float*)d_in[4];
    const float* q_up_b   = (const float*)d_in[5];
    const float* kv_down_w= (const float*)d_in[6];
    const float* kv_down_b= (const float*)d_in[7];
    const float* kv_norm_w= (const float*)d_in[8];
    const float* kv_up_w  = (const float*)d_in[9];
    const float* kv_up_b  = (const float*)d_in[10];
    const float* k_rope_w = (const float*)d_in[11];
    const float* k_rope_b = (const float*)d_in[12];
    const float* out_w    = (const float*)d_in[13];
    const float* out_b    = (const float*)d_in[14];

    char* ws = (char*)d_ws;
    u16* xbf    = (u16*)(ws + 0);          // 16.78 MB ; later reused as vT
    u16* wcat   = (u16*)(ws + 16777216);   // 10.49 MB; dead at attn -> PART0
    u16* quw    = (u16*)(ws + 27262976);   // 4.19 MB ; dead at attn
    u16* kvuw   = (u16*)(ws + 31457280);   // 3.15 MB ; dead at attn
    u16* outw   = (u16*)(ws + 34603008);   // 8.39 MB (live until final GEMM)
    float* bcat = (float*)(ws + 42991616); // 10 KB
    float* dcat = (float*)(ws + 43008000); // 25.17 MB; reused as attnbuf + P1B
    u16* cq     = (u16*)(ws + 68173824);   // 8.39 MB ; dead at attn -> P1A
    u16* ckv    = (u16*)(ws + 76562432);   // 4.19 MB ; dead at attn -> P1A
    u16* qbuf   = (u16*)(ws + 80756736);   // 16.78 MB
    u16* kvbuf  = (u16*)(ws + 97533952);   // 25.17 MB
    u16* krbuf  = (u16*)(ws + 122699776);  // 8.39 MB  (end 131,088,384)
    u16* vT     = (u16*)(ws + 0);          // alias xbf (dead after gemm_down)
    u16* attnbuf= (u16*)(ws + 43008000);   // alias dcat
    // attention K-split partial buffers (all in regions dead at attn time)
    float* part0 = (float*)(ws + 16777216);  // 16 MB  (wcat/quw/part of kvuw)
    float* mlbuf = (float*)(ws + 33554432);  // 512 KB (rest of kvuw region)
    float* p1a   = (float*)(ws + 68173824);  // 12.58 MB (cq+ckv), pi<192
    float* p1b   = (float*)(ws + 59785216);  // 4 MB used (spare after attnbuf), pi>=192

    cvt_all<<<20992, 256, 0, stream>>>(
        x, xbf,
        q_down_w,  wcat,
        kv_down_w, wcat + 1024 * 2048,
        k_rope_w,  wcat + 1536 * 2048,
        q_up_w,    quw,
        kv_up_w,   kvuw,
        out_w,     outw);
    build_bcat<<<10, 256, 0, stream>>>(q_down_b, kv_down_b, k_rope_b, bcat);

    // fused down projections: x @ [q_down|kv_down|k_rope]^T
    gemm_down<<<dim3(20, 32), 256, 0, stream>>>(xbf, wcat, bcat, dcat, krbuf);
    rmsnorm_bf16<1024><<<MROWS, 256, 0, stream>>>(dcat, 1536, q_norm_w, cq);
    rmsnorm_bf16<512><<<MROWS, 256, 0, stream>>>(dcat + 1024, 1536, kv_norm_w, ckv);
    // up projections
    gemm_bt<u16><<<dim3(16, 32), 256, 0, stream>>>(cq, quw, q_up_b, qbuf, MROWS, 2048, 1024);
    gemm_bt<u16><<<dim3(24, 32), 256, 0, stream>>>(ckv, kvuw, kv_up_b, kvbuf, MROWS, 3072, 512);
    // V transpose (vT aliases xbf; xbf dead after gemm_down)
    transpose_v<<<dim3(64, 32), 256, 0, stream>>>(kvbuf, vT);
    // attention: 512 uniform blocks (17 k-tiles each), 2 blocks/CU
    mla_attn<<<dim3(16, 32), 256, 0, stream>>>(qbuf, kvbuf, krbuf, vT, attnbuf,
                                               part0, p1a, p1b, mlbuf);
    attn_merge<<<dim3(4, 256), 256, 0, stream>>>(part0, p1a, p1b, mlbuf, attnbuf);
    // output projection
    gemm_bt<float><<<dim3(16, 32), 256, 0, stream>>>(attnbuf, outw, out_b, (float*)d_out, MROWS, 2048, 2048);
}

// Round 7
// 285.398 us; speedup vs baseline: 1.0572x; 1.0572x over previous
//
#include <hip/hip_runtime.h>
#include <hip/hip_bf16.h>

typedef __attribute__((ext_vector_type(8))) short bf16x8;
typedef __attribute__((ext_vector_type(4))) float f32x4;
typedef unsigned short u16;

#define RMS_EPS 1.1920929e-07f

constexpr int Bb = 2, Ss = 2048, DM = 2048, NH = 16;
constexpr int MROWS = Bb * Ss; // 4096

__device__ __forceinline__ u16 f2bf(float f) {
    __hip_bfloat16 h = __float2bfloat16(f);
    return *reinterpret_cast<u16*>(&h);
}

__device__ __forceinline__ float exp2_fast(float x) {
    float r; asm("v_exp_f32 %0, %1" : "=v"(r) : "v"(x)); return r;
}

__device__ __forceinline__ void gload16(const void* g, void* l) {
    __builtin_amdgcn_global_load_lds(
        (const __attribute__((address_space(1))) unsigned int*)g,
        (__attribute__((address_space(3))) unsigned int*)l, 16, 0, 0);
}

// ---------------- merged fp32 -> bf16 convert (7 segments, sizes fixed) -------
__global__ __launch_bounds__(256) void cvt_all(
    const float* __restrict__ s0, u16* __restrict__ d0,
    const float* __restrict__ s1, u16* __restrict__ d1,
    const float* __restrict__ s2, u16* __restrict__ d2,
    const float* __restrict__ s3, u16* __restrict__ d3,
    const float* __restrict__ s4, u16* __restrict__ d4,
    const float* __restrict__ s5, u16* __restrict__ d5,
    const float* __restrict__ s6, u16* __restrict__ d6)
{
    int i = blockIdx.x * 256 + threadIdx.x;   // float4 index; grid covers exactly 5373952
    const float* s; u16* d; int off;
    if (i < 2097152)      { s = s0; d = d0; off = 0; }
    else if (i < 2621440) { s = s1; d = d1; off = 2097152; }
    else if (i < 2883584) { s = s2; d = d2; off = 2621440; }
    else if (i < 3407872) { s = s3; d = d3; off = 2883584; }
    else if (i < 3932160) { s = s4; d = d4; off = 3407872; }
    else if (i < 4325376) { s = s5; d = d5; off = 3932160; }
    else                  { s = s6; d = d6; off = 4325376; }
    int j = i - off;
    float4 v = reinterpret_cast<const float4*>(s)[j];
    ushort4 o;
    o.x = f2bf(v.x); o.y = f2bf(v.y); o.z = f2bf(v.z); o.w = f2bf(v.w);
    reinterpret_cast<ushort4*>(d)[j] = o;
}

__global__ void build_bcat(const float* __restrict__ qb, const float* __restrict__ kvb,
                           const float* __restrict__ krb, float* __restrict__ bcat) {
    int i = blockIdx.x * 256 + threadIdx.x;
    if (i < 1024) bcat[i] = qb[i];
    else if (i < 1536) bcat[i] = kvb[i - 1024];
    else if (i < 2560) bcat[i] = krb[i - 1536];
}

// ---------------- GEMM: C(M,N) = A(M,K) * Bt(N,K)^T + bias ----------------
template <typename OutT>
__global__ __launch_bounds__(256) void gemm_bt(
    const u16* __restrict__ A, const u16* __restrict__ Bt,
    const float* __restrict__ bias, OutT* __restrict__ C,
    int M, int N, int K)
{
    __shared__ alignas(16) u16 sA[128 * 32];
    __shared__ alignas(16) u16 sB[128 * 32];
    const int tid = threadIdx.x;
    const int lane = tid & 63;
    const int w = tid >> 6;
    const int wr = w >> 1, wc = w & 1;
    const int l16 = lane & 15, lq = lane >> 4;
    const int tileM = blockIdx.y * 128;
    const int tileN = blockIdx.x * 128;

    f32x4 acc[4][4];
#pragma unroll
    for (int m = 0; m < 4; m++)
#pragma unroll
        for (int n = 0; n < 4; n++)
#pragma unroll
            for (int r = 0; r < 4; r++) acc[m][n][r] = 0.f;

    const int srow = w * 16 + (lane >> 2);
    const int scol = (lane & 3) * 8;
    const u16* gA0 = A + (size_t)(tileM + srow) * K + scol;
    const u16* gA1 = A + (size_t)(tileM + srow + 64) * K + scol;
    const u16* gB0 = Bt + (size_t)(tileN + srow) * K + scol;
    const u16* gB1 = Bt + (size_t)(tileN + srow + 64) * K + scol;
    u16* lA0 = sA + w * 512;
    u16* lA1 = sA + 2048 + w * 512;
    u16* lB0 = sB + w * 512;
    u16* lB1 = sB + 2048 + w * 512;

    int aoff[4], boff[4];
#pragma unroll
    for (int m = 0; m < 4; m++) aoff[m] = (wr * 64 + m * 16 + l16) * 32 + lq * 8;
#pragma unroll
    for (int n = 0; n < 4; n++) boff[n] = (wc * 64 + n * 16 + l16) * 32 + lq * 8;

    const int nk = K >> 5;
    for (int kk = 0; kk < nk; ++kk) {
        __syncthreads();
        gload16(gA0, lA0);
        gload16(gA1, lA1);
        gload16(gB0, lB0);
        gload16(gB1, lB1);
        gA0 += 32; gA1 += 32; gB0 += 32; gB1 += 32;
        __syncthreads();
        bf16x8 af[4], bfr[4];
#pragma unroll
        for (int m = 0; m < 4; m++) af[m] = *(const bf16x8*)&sA[aoff[m]];
#pragma unroll
        for (int n = 0; n < 4; n++) bfr[n] = *(const bf16x8*)&sB[boff[n]];
        __builtin_amdgcn_s_setprio(1);
#pragma unroll
        for (int m = 0; m < 4; m++)
#pragma unroll
            for (int n = 0; n < 4; n++)
                acc[m][n] = __builtin_amdgcn_mfma_f32_16x16x32_bf16(af[m], bfr[n], acc[m][n], 0, 0, 0);
        __builtin_amdgcn_s_setprio(0);
    }

#pragma unroll
    for (int n = 0; n < 4; n++) {
        int col = tileN + wc * 64 + n * 16 + l16;
        float bv = bias ? bias[col] : 0.f;
#pragma unroll
        for (int m = 0; m < 4; m++) {
            int rowb = tileM + wr * 64 + m * 16 + (lq << 2);
#pragma unroll
            for (int r = 0; r < 4; r++) {
                float v = acc[m][n][r] + bv;
                if constexpr (sizeof(OutT) == 2)
                    C[(size_t)(rowb + r) * N + col] = (OutT)f2bf(v);
                else
                    C[(size_t)(rowb + r) * N + col] = (OutT)v;
            }
        }
    }
}

// ---------------- fused down-proj GEMM: N=2560 (1024 q | 512 kv | 1024 rope) ----
__global__ __launch_bounds__(256) void gemm_down(
    const u16* __restrict__ A, const u16* __restrict__ Bt,
    const float* __restrict__ bcat, float* __restrict__ dcat,
    u16* __restrict__ krbuf)
{
    constexpr int K = 2048;
    __shared__ alignas(16) u16 sA[128 * 32];
    __shared__ alignas(16) u16 sB[128 * 32];
    const int tid = threadIdx.x;
    const int lane = tid & 63;
    const int w = tid >> 6;
    const int wr = w >> 1, wc = w & 1;
    const int l16 = lane & 15, lq = lane >> 4;
    const int tileM = blockIdx.y * 128;
    const int tileN = blockIdx.x * 128;

    f32x4 acc[4][4];
#pragma unroll
    for (int m = 0; m < 4; m++)
#pragma unroll
        for (int n = 0; n < 4; n++)
#pragma unroll
            for (int r = 0; r < 4; r++) acc[m][n][r] = 0.f;

    const int srow = w * 16 + (lane >> 2);
    const int scol = (lane & 3) * 8;
    const u16* gA0 = A + (size_t)(tileM + srow) * K + scol;
    const u16* gA1 = A + (size_t)(tileM + srow + 64) * K + scol;
    const u16* gB0 = Bt + (size_t)(tileN + srow) * K + scol;
    const u16* gB1 = Bt + (size_t)(tileN + srow + 64) * K + scol;
    u16* lA0 = sA + w * 512;
    u16* lA1 = sA + 2048 + w * 512;
    u16* lB0 = sB + w * 512;
    u16* lB1 = sB + 2048 + w * 512;

    int aoff[4], boff[4];
#pragma unroll
    for (int m = 0; m < 4; m++) aoff[m] = (wr * 64 + m * 16 + l16) * 32 + lq * 8;
#pragma unroll
    for (int n = 0; n < 4; n++) boff[n] = (wc * 64 + n * 16 + l16) * 32 + lq * 8;

    const int nk = K >> 5;
    for (int kk = 0; kk < nk; ++kk) {
        __syncthreads();
        gload16(gA0, lA0);
        gload16(gA1, lA1);
        gload16(gB0, lB0);
        gload16(gB1, lB1);
        gA0 += 32; gA1 += 32; gB0 += 32; gB1 += 32;
        __syncthreads();
        bf16x8 af[4], bfr[4];
#pragma unroll
        for (int m = 0; m < 4; m++) af[m] = *(const bf16x8*)&sA[aoff[m]];
#pragma unroll
        for (int n = 0; n < 4; n++) bfr[n] = *(const bf16x8*)&sB[boff[n]];
        __builtin_amdgcn_s_setprio(1);
#pragma unroll
        for (int m = 0; m < 4; m++)
#pragma unroll
            for (int n = 0; n < 4; n++)
                acc[m][n] = __builtin_amdgcn_mfma_f32_16x16x32_bf16(af[m], bfr[n], acc[m][n], 0, 0, 0);
        __builtin_amdgcn_s_setprio(0);
    }

    const bool isrope = (tileN >= 1536);
#pragma unroll
    for (int n = 0; n < 4; n++) {
        int col = tileN + wc * 64 + n * 16 + l16;
        float bv = bcat[col];
#pragma unroll
        for (int m = 0; m < 4; m++) {
            int rowb = tileM + wr * 64 + m * 16 + (lq << 2);
#pragma unroll
            for (int r = 0; r < 4; r++) {
                float v = acc[m][n][r] + bv;
                if (!isrope) dcat[(size_t)(rowb + r) * 1536 + col] = v;
                else         krbuf[(size_t)(rowb + r) * 1024 + (col - 1536)] = f2bf(v);
            }
        }
    }
}

// ---------------- RMS norm (row-wise, strided in), fp32 in -> bf16 out --------
template <int C>
__global__ __launch_bounds__(256) void rmsnorm_bf16(
    const float* __restrict__ in, int istride, const float* __restrict__ wgt, u16* __restrict__ out)
{
    const int row = blockIdx.x;
    const int tid = threadIdx.x;
    constexpr int PER = C / 256;
    const float* p = in + (size_t)row * istride;
    float v[PER];
    float ss = 0.f;
#pragma unroll
    for (int i = 0; i < PER; i++) { v[i] = p[tid + i * 256]; ss += v[i] * v[i]; }
#pragma unroll
    for (int o = 32; o; o >>= 1) ss += __shfl_xor(ss, o, 64);
    __shared__ float red[4];
    if ((tid & 63) == 0) red[tid >> 6] = ss;
    __syncthreads();
    float tot = red[0] + red[1] + red[2] + red[3];
    float inv = rsqrtf(tot / (float)C + RMS_EPS);
    u16* q = out + (size_t)row * C;
#pragma unroll
    for (int i = 0; i < PER; i++) {
        int c = tid + i * 256;
        q[c] = f2bf(v[i] * inv * wgt[c]);
    }
}

// ---------------- V transpose: kvbuf[token][h*192+64+d] -> vT[(h*128+d)*4096+token]
__global__ __launch_bounds__(256) void transpose_v(
    const u16* __restrict__ kvbuf, u16* __restrict__ vT)
{
    __shared__ alignas(16) u16 tile[64][72];
    const int tid = threadIdx.x;
    const int t0 = blockIdx.x * 64;
    const int h = blockIdx.y >> 1, dh = blockIdx.y & 1;
    const int trow = tid >> 2, c8 = (tid & 3) * 8;
    const u16* src = kvbuf + (size_t)(t0 + trow) * 3072 + h * 192 + 64 + dh * 64 + c8;
    *(bf16x8*)&tile[trow][c8]      = *(const bf16x8*)src;
    *(bf16x8*)&tile[trow][c8 + 32] = *(const bf16x8*)(src + 32);
    __syncthreads();
    const int drow = tid >> 2, tc8 = (tid & 3) * 8;
    bf16x8 a, b2;
#pragma unroll
    for (int j = 0; j < 8; j++) {
        a[j]  = (short)tile[tc8 + j][drow];
        b2[j] = (short)tile[tc8 + 32 + j][drow];
    }
    u16* dst = vT + (size_t)(h * 128 + dh * 64 + drow) * MROWS + t0 + tc8;
    *(bf16x8*)dst = a;
    *(bf16x8*)(dst + 32) = b2;
}

// ---------------- causal flash attention ----------------
// 1024 blocks = (32 bh) x (32 qt permuted). QBLK=64 (4 waves x 16 q), KT=64.
// Resource-tuned for 4 blocks/CU: LDS 40KB (4x40=160), target VGPR <= 128.
// qt permutation: CU-coresident blocks {y, y+8, y+16, y+24} get qt sets
// {2i, 31-2i, 2i+1, 30-2i} -> every CU processes exactly 66 k-tiles.
// XCD/L2: flat%8 = bh%8 -> 4 bh per XCD = 4 MB KV = one L2.
__global__ __launch_bounds__(256) void mla_attn(
    const u16* __restrict__ qbuf,   // (4096, 2048) head-major h*128
    const u16* __restrict__ kvbuf,  // (4096, 3072) per head 192: knope(64) v(128)
    const u16* __restrict__ krbuf,  // (4096, 1024) per head 64
    const u16* __restrict__ vT,     // (h*128+d, 4096 tokens)
    u16* __restrict__ obuf)         // (4096, 2048)
{
    const int bh = blockIdx.x;
    const int yy = blockIdx.y;
    const int ii = yy & 7, jj = yy >> 3;
    const int qt = (jj == 0) ? (ii * 2) : (jj == 1) ? (31 - ii * 2)
                 : (jj == 2) ? (ii * 2 + 1) : (30 - ii * 2);
    const int b = bh >> 4, h = bh & 15;
    const int tid = threadIdx.x, lane = tid & 63, w = tid >> 6;
    const int l16 = lane & 15, lq = lane >> 4;

    __shared__ alignas(16) u16 sK[64 * 128];
    __shared__ alignas(16) u16 sVt[128 * 64];
    __shared__ alignas(16) u16 sPT[4][16 * 64];

    const int rowbase = b * Ss;
    const int q0 = qt * 64;
    char* pbase = (char*)sPT[w];

    const int sr = tid >> 2, sc = (tid & 3) * 32;   // K staging
    const int vd = tid >> 1, vh = (tid & 1) * 32;   // V staging
    const float C1 = 0.12751742f;    // softmax_scale * log2(e)
    const float THRR = 90.5f;        // defer-max threshold (raw score units)

    bf16x8 qf[4];
    {
        const u16* qp = qbuf + (size_t)(rowbase + q0 + w * 16 + l16) * 2048 + h * 128 + lq * 8;
#pragma unroll
        for (int c = 0; c < 4; c++) qf[c] = *(const bf16x8*)(qp + c * 32);
    }
    float mi = -3e38f, li = 0.f;
    f32x4 o[8];
#pragma unroll
    for (int d = 0; d < 8; d++)
#pragma unroll
        for (int r = 0; r < 4; r++) o[d][r] = 0.f;

    bf16x8 kr[4], vr[4];
    {   // prologue: tile 0 -> regs
        const int krow = rowbase + sr;
        const u16* src = (sc < 64)
            ? kvbuf + (size_t)krow * 3072 + h * 192 + sc
            : krbuf + (size_t)krow * 1024 + h * 64 + (sc - 64);
#pragma unroll
        for (int j = 0; j < 4; j++) kr[j] = *(const bf16x8*)(src + j * 8);
        const u16* vsrc = vT + (size_t)(h * 128 + vd) * MROWS + rowbase + vh;
#pragma unroll
        for (int j = 0; j < 4; j++) vr[j] = *(const bf16x8*)(vsrc + j * 8);
    }

    for (int kt = 0; kt <= qt; ++kt) {
        __syncthreads();
#pragma unroll
        for (int j = 0; j < 4; j++) {
            int byteoff = sr * 256 + (sc + j * 8) * 2;
            *(bf16x8*)((char*)sK + (byteoff ^ ((sr & 7) << 4))) = kr[j];
        }
#pragma unroll
        for (int j = 0; j < 4; j++) {
            int byteoff = vd * 128 + (vh + j * 8) * 2;
            *(bf16x8*)((char*)sVt + (byteoff ^ ((vd & 7) << 4))) = vr[j];
        }
        __syncthreads();
        if (kt < qt) {   // prefetch next tile into regs (hides under compute)
            const int krow = rowbase + (kt + 1) * 64 + sr;
            const u16* src = (sc < 64)
                ? kvbuf + (size_t)krow * 3072 + h * 192 + sc
                : krbuf + (size_t)krow * 1024 + h * 64 + (sc - 64);
#pragma unroll
            for (int j = 0; j < 4; j++) kr[j] = *(const bf16x8*)(src + j * 8);
            const u16* vsrc = vT + (size_t)(h * 128 + vd) * MROWS + rowbase + (kt + 1) * 64 + vh;
#pragma unroll
            for (int j = 0; j < 4; j++) vr[j] = *(const bf16x8*)(vsrc + j * 8);
        }

        // QK^T swapped: A=K, B=Q -> D[k][q]; lane: q=l16, k=n*16+lq*4+r
        f32x4 scf[4];
#pragma unroll
        for (int n = 0; n < 4; n++)
#pragma unroll
            for (int r = 0; r < 4; r++) scf[n][r] = 0.f;
        __builtin_amdgcn_s_setprio(1);
#pragma unroll
        for (int n = 0; n < 4; n++) {
#pragma unroll
            for (int c = 0; c < 4; c++) {
                int row = n * 16 + l16;
                int byteoff = row * 256 + (c * 32 + lq * 8) * 2;
                bf16x8 kf = *(const bf16x8*)((char*)sK + (byteoff ^ ((row & 7) << 4)));
                scf[n] = __builtin_amdgcn_mfma_f32_16x16x32_bf16(kf, qf[c], scf[n], 0, 0, 0);
            }
        }
        __builtin_amdgcn_s_setprio(0);

        // mask only the diagonal tile (wave-uniform branch)
        if (kt == qt) {
            const int qg = w * 16 + l16;
#pragma unroll
            for (int n = 0; n < 4; n++)
#pragma unroll
                for (int r = 0; r < 4; r++) {
                    int kg = n * 16 + lq * 4 + r;
                    if (kg > qg) scf[n][r] = -3e38f;
                }
        }
        // online softmax (exp2 domain) with T13 defer-max
        float mx = mi;
#pragma unroll
        for (int n = 0; n < 4; n++)
#pragma unroll
            for (int r = 0; r < 4; r++) mx = fmaxf(mx, scf[n][r]);
        mx = fmaxf(mx, __shfl_xor(mx, 16, 64));
        mx = fmaxf(mx, __shfl_xor(mx, 32, 64));
        if (!__all(mx - mi <= THRR)) {
            float f = exp2_fast((mi - mx) * C1);
            li *= f;
#pragma unroll
            for (int d = 0; d < 8; d++)
#pragma unroll
                for (int r = 0; r < 4; r++) o[d][r] *= f;
            mi = mx;
        }
        float mc = mi * C1;
        float rs = 0.f;
#pragma unroll
        for (int n = 0; n < 4; n++)
#pragma unroll
            for (int r = 0; r < 4; r++) {
                float pv = exp2_fast(__fmaf_rn(scf[n][r], C1, -mc));
                scf[n][r] = pv;
                rs += pv;
            }
        rs += __shfl_xor(rs, 16, 64);
        rs += __shfl_xor(rs, 32, 64);
        li += rs;

        // P^T -> wave-private LDS (vectorized 8B writes), no barrier needed
#pragma unroll
        for (int n = 0; n < 4; n++) {
            ushort4 pk;
            pk.x = f2bf(scf[n][0]); pk.y = f2bf(scf[n][1]);
            pk.z = f2bf(scf[n][2]); pk.w = f2bf(scf[n][3]);
            int byteoff = l16 * 128 + n * 32 + lq * 8;
            *(ushort4*)(pbase + (byteoff ^ ((l16 & 7) << 4))) = pk;
        }
        // PV swapped: A=V^T, B=P^T -> D[d][q]
        __builtin_amdgcn_s_setprio(1);
#pragma unroll
        for (int c = 0; c < 2; c++) {
            int pbyte = l16 * 128 + (c * 32 + lq * 8) * 2;
            bf16x8 pf = *(const bf16x8*)(pbase + (pbyte ^ ((l16 & 7) << 4)));
#pragma unroll
            for (int d = 0; d < 8; d++) {
                int vrow = d * 16 + l16;
                int vbyte = vrow * 128 + (c * 32 + lq * 8) * 2;
                bf16x8 vf = *(const bf16x8*)((char*)sVt + (vbyte ^ ((vrow & 7) << 4)));
                o[d] = __builtin_amdgcn_mfma_f32_16x16x32_bf16(vf, pf, o[d], 0, 0, 0);
            }
        }
        __builtin_amdgcn_s_setprio(0);
    }
    // epilogue: lane holds O^T[d][q=l16]; d = db*16 + lq*4 + r
    float invl = 1.f / li;
    u16* op = obuf + (size_t)(rowbase + q0 + w * 16 + l16) * 2048 + h * 128;
#pragma unroll
    for (int d = 0; d < 8; d++) {
        ushort4 ok;
        ok.x = f2bf(o[d][0] * invl); ok.y = f2bf(o[d][1] * invl);
        ok.z = f2bf(o[d][2] * invl); ok.w = f2bf(o[d][3] * invl);
        *(ushort4*)(op + d * 16 + lq * 4) = ok;
    }
}

// ---------------- launch ----------------
extern "C" void kernel_launch(void* const* d_in, const int* in_sizes, int n_in,
                              void* d_out, int out_size, void* d_ws, size_t ws_size,
                              hipStream_t stream) {
    const float* x        = (const float*)d_in[0];
    const float* q_down_w = (const float*)d_in[1];
    const float* q_down_b = (const float*)d_in[2];
    const float* q_norm_w = (const float*)d_in[3];
    const float* q_up_w   = (const float*)d_in[4];
    const float* q_up_b   = (const float*)d_in[5];
    const float* kv_down_w= (const float*)d_in[6];
    const float* kv_down_b= (const float*)d_in[7];
    const float* kv_norm_w= (const float*)d_in[8];
    const float* kv_up_w  = (const float*)d_in[9];
    const float* kv_up_b  = (const float*)d_in[10];
    const float* k_rope_w = (const float*)d_in[11];
    const float* k_rope_b = (const float*)d_in[12];
    const float* out_w    = (const float*)d_in[13];
    const float* out_b    = (const float*)d_in[14];

    char* ws = (char*)d_ws;
    u16* xbf    = (u16*)(ws + 0);          // 16.78 MB ; later reused as vT
    u16* wcat   = (u16*)(ws + 16777216);   // 10.49 MB (2560x2048 bf16)
    u16* quw    = (u16*)(ws + 27262976);   // 4.19 MB
    u16* kvuw   = (u16*)(ws + 31457280);   // 3.15 MB
    u16* outw   = (u16*)(ws + 34603008);   // 8.39 MB
    float* bcat = (float*)(ws + 42991616); // 10 KB (pad to 16 KB)
    float* dcat = (float*)(ws + 43008000); // 25.17 MB (4096x1536 f32); reused as attnbuf
    u16* cq     = (u16*)(ws + 68173824);   // 8.39 MB
    u16* ckv    = (u16*)(ws + 76562432);   // 4.19 MB
    u16* qbuf   = (u16*)(ws + 80756736);   // 16.78 MB
    u16* kvbuf  = (u16*)(ws + 97533952);   // 25.17 MB
    u16* krbuf  = (u16*)(ws + 122699776);  // 8.39 MB  (end 131,088,384)
    u16* vT     = (u16*)(ws + 0);          // alias xbf (dead after gemm_down)
    u16* attnbuf= (u16*)(ws + 43008000);   // alias dcat (dead after rmsnorms)

    cvt_all<<<20992, 256, 0, stream>>>(
        x, xbf,
        q_down_w,  wcat,
        kv_down_w, wcat + 1024 * 2048,
        k_rope_w,  wcat + 1536 * 2048,
        q_up_w,    quw,
        kv_up_w,   kvuw,
        out_w,     outw);
    build_bcat<<<10, 256, 0, stream>>>(q_down_b, kv_down_b, k_rope_b, bcat);

    // fused down projections: x @ [q_down|kv_down|k_rope]^T
    gemm_down<<<dim3(20, 32), 256, 0, stream>>>(xbf, wcat, bcat, dcat, krbuf);
    rmsnorm_bf16<1024><<<MROWS, 256, 0, stream>>>(dcat, 1536, q_norm_w, cq);
    rmsnorm_bf16<512><<<MROWS, 256, 0, stream>>>(dcat + 1024, 1536, kv_norm_w, ckv);
    // up projections
    gemm_bt<u16><<<dim3(16, 32), 256, 0, stream>>>(cq, quw, q_up_b, qbuf, MROWS, 2048, 1024);
    gemm_bt<u16><<<dim3(24, 32), 256, 0, stream>>>(ckv, kvuw, kv_up_b, kvbuf, MROWS, 3072, 512);
    // V transpose (vT aliases xbf; xbf dead after gemm_down)
    transpose_v<<<dim3(64, 32), 256, 0, stream>>>(kvbuf, vT);
    // attention: 1024 blocks (32 bh x 32 qt permuted), 4 blocks/CU
    mla_attn<<<dim3(32, 32), 256, 0, stream>>>(qbuf, kvbuf, krbuf, vT, attnbuf);
    // output projection
    gemm_bt<float><<<dim3(16, 32), 256, 0, stream>>>(attnbuf, outw, out_b, (float*)d_out, MROWS, 2048, 2048);
}

// Round 8
// 266.758 us; speedup vs baseline: 1.1310x; 1.0699x over previous
//
#include <hip/hip_runtime.h>
#include <hip/hip_bf16.h>

typedef __attribute__((ext_vector_type(8))) short bf16x8;
typedef __attribute__((ext_vector_type(4))) float f32x4;
typedef __attribute__((ext_vector_type(16))) float f32x16;
typedef unsigned short u16;
typedef unsigned int u32;

#define RMS_EPS 1.1920929e-07f

constexpr int Bb = 2, Ss = 2048, DM = 2048, NH = 16;
constexpr int MROWS = Bb * Ss; // 4096

__device__ __forceinline__ u16 f2bf(float f) {
    __hip_bfloat16 h = __float2bfloat16(f);
    return *reinterpret_cast<u16*>(&h);
}

__device__ __forceinline__ float exp2_fast(float x) {
    float r; asm("v_exp_f32 %0, %1" : "=v"(r) : "v"(x)); return r;
}

__device__ __forceinline__ void gload16(const void* g, void* l) {
    __builtin_amdgcn_global_load_lds(
        (const __attribute__((address_space(1))) unsigned int*)g,
        (__attribute__((address_space(3))) unsigned int*)l, 16, 0, 0);
}

// ---------------- merged fp32 -> bf16 convert (7 segments, sizes fixed) -------
__global__ __launch_bounds__(256) void cvt_all(
    const float* __restrict__ s0, u16* __restrict__ d0,
    const float* __restrict__ s1, u16* __restrict__ d1,
    const float* __restrict__ s2, u16* __restrict__ d2,
    const float* __restrict__ s3, u16* __restrict__ d3,
    const float* __restrict__ s4, u16* __restrict__ d4,
    const float* __restrict__ s5, u16* __restrict__ d5,
    const float* __restrict__ s6, u16* __restrict__ d6)
{
    int i = blockIdx.x * 256 + threadIdx.x;   // float4 index; grid covers exactly 5373952
    const float* s; u16* d; int off;
    if (i < 2097152)      { s = s0; d = d0; off = 0; }
    else if (i < 2621440) { s = s1; d = d1; off = 2097152; }
    else if (i < 2883584) { s = s2; d = d2; off = 2621440; }
    else if (i < 3407872) { s = s3; d = d3; off = 2883584; }
    else if (i < 3932160) { s = s4; d = d4; off = 3407872; }
    else if (i < 4325376) { s = s5; d = d5; off = 3932160; }
    else                  { s = s6; d = d6; off = 4325376; }
    int j = i - off;
    float4 v = reinterpret_cast<const float4*>(s)[j];
    ushort4 o;
    o.x = f2bf(v.x); o.y = f2bf(v.y); o.z = f2bf(v.z); o.w = f2bf(v.w);
    reinterpret_cast<ushort4*>(d)[j] = o;
}

__global__ void build_bcat(const float* __restrict__ qb, const float* __restrict__ kvb,
                           const float* __restrict__ krb, float* __restrict__ bcat) {
    int i = blockIdx.x * 256 + threadIdx.x;
    if (i < 1024) bcat[i] = qb[i];
    else if (i < 1536) bcat[i] = kvb[i - 1024];
    else if (i < 2560) bcat[i] = krb[i - 1536];
}

// XCD-chunked bijective block remap (T1). Requires nwg % 8 == 0.
__device__ __forceinline__ void xcd_remap(int& bx, int& by) {
    int nx = gridDim.x, ny = gridDim.y;
    int nwg = nx * ny;
    if ((nwg & 7) != 0) return;
    int flat = blockIdx.x + nx * blockIdx.y;
    int chunk = nwg >> 3;
    int wg = (flat & 7) * chunk + (flat >> 3);
    by = wg % ny;          // M-tile fastest within an XCD chunk
    bx = wg / ny;          // few N-columns per XCD -> B-panel L2 reuse
}

// ---------------- GEMM: C(M,N) = A(M,K) * Bt(N,K)^T + bias ----------------
template <typename OutT>
__global__ __launch_bounds__(256) void gemm_bt(
    const u16* __restrict__ A, const u16* __restrict__ Bt,
    const float* __restrict__ bias, OutT* __restrict__ C,
    int M, int N, int K)
{
    __shared__ alignas(16) u16 sA[128 * 32];
    __shared__ alignas(16) u16 sB[128 * 32];
    const int tid = threadIdx.x;
    const int lane = tid & 63;
    const int w = tid >> 6;
    const int wr = w >> 1, wc = w & 1;
    const int l16 = lane & 15, lq = lane >> 4;
    int bx = blockIdx.x, by = blockIdx.y;
    xcd_remap(bx, by);
    const int tileM = by * 128;
    const int tileN = bx * 128;

    f32x4 acc[4][4];
#pragma unroll
    for (int m = 0; m < 4; m++)
#pragma unroll
        for (int n = 0; n < 4; n++)
#pragma unroll
            for (int r = 0; r < 4; r++) acc[m][n][r] = 0.f;

    const int srow = w * 16 + (lane >> 2);
    const int scol = (lane & 3) * 8;
    const u16* gA0 = A + (size_t)(tileM + srow) * K + scol;
    const u16* gA1 = A + (size_t)(tileM + srow + 64) * K + scol;
    const u16* gB0 = Bt + (size_t)(tileN + srow) * K + scol;
    const u16* gB1 = Bt + (size_t)(tileN + srow + 64) * K + scol;
    u16* lA0 = sA + w * 512;
    u16* lA1 = sA + 2048 + w * 512;
    u16* lB0 = sB + w * 512;
    u16* lB1 = sB + 2048 + w * 512;

    int aoff[4], boff[4];
#pragma unroll
    for (int m = 0; m < 4; m++) aoff[m] = (wr * 64 + m * 16 + l16) * 32 + lq * 8;
#pragma unroll
    for (int n = 0; n < 4; n++) boff[n] = (wc * 64 + n * 16 + l16) * 32 + lq * 8;

    const int nk = K >> 5;
    for (int kk = 0; kk < nk; ++kk) {
        __syncthreads();
        gload16(gA0, lA0);
        gload16(gA1, lA1);
        gload16(gB0, lB0);
        gload16(gB1, lB1);
        gA0 += 32; gA1 += 32; gB0 += 32; gB1 += 32;
        __syncthreads();
        bf16x8 af[4], bfr[4];
#pragma unroll
        for (int m = 0; m < 4; m++) af[m] = *(const bf16x8*)&sA[aoff[m]];
#pragma unroll
        for (int n = 0; n < 4; n++) bfr[n] = *(const bf16x8*)&sB[boff[n]];
        __builtin_amdgcn_s_setprio(1);
#pragma unroll
        for (int m = 0; m < 4; m++)
#pragma unroll
            for (int n = 0; n < 4; n++)
                acc[m][n] = __builtin_amdgcn_mfma_f32_16x16x32_bf16(af[m], bfr[n], acc[m][n], 0, 0, 0);
        __builtin_amdgcn_s_setprio(0);
    }

#pragma unroll
    for (int n = 0; n < 4; n++) {
        int col = tileN + wc * 64 + n * 16 + l16;
        float bv = bias ? bias[col] : 0.f;
#pragma unroll
        for (int m = 0; m < 4; m++) {
            int rowb = tileM + wr * 64 + m * 16 + (lq << 2);
#pragma unroll
            for (int r = 0; r < 4; r++) {
                float v = acc[m][n][r] + bv;
                if constexpr (sizeof(OutT) == 2)
                    C[(size_t)(rowb + r) * N + col] = (OutT)f2bf(v);
                else
                    C[(size_t)(rowb + r) * N + col] = (OutT)v;
            }
        }
    }
}

// ---------------- fused down-proj GEMM: N=2560 (1024 q | 512 kv | 1024 rope) ----
__global__ __launch_bounds__(256) void gemm_down(
    const u16* __restrict__ A, const u16* __restrict__ Bt,
    const float* __restrict__ bcat, float* __restrict__ dcat,
    u16* __restrict__ krbuf)
{
    constexpr int K = 2048;
    __shared__ alignas(16) u16 sA[128 * 32];
    __shared__ alignas(16) u16 sB[128 * 32];
    const int tid = threadIdx.x;
    const int lane = tid & 63;
    const int w = tid >> 6;
    const int wr = w >> 1, wc = w & 1;
    const int l16 = lane & 15, lq = lane >> 4;
    int bx = blockIdx.x, by = blockIdx.y;
    xcd_remap(bx, by);
    const int tileM = by * 128;
    const int tileN = bx * 128;

    f32x4 acc[4][4];
#pragma unroll
    for (int m = 0; m < 4; m++)
#pragma unroll
        for (int n = 0; n < 4; n++)
#pragma unroll
            for (int r = 0; r < 4; r++) acc[m][n][r] = 0.f;

    const int srow = w * 16 + (lane >> 2);
    const int scol = (lane & 3) * 8;
    const u16* gA0 = A + (size_t)(tileM + srow) * K + scol;
    const u16* gA1 = A + (size_t)(tileM + srow + 64) * K + scol;
    const u16* gB0 = Bt + (size_t)(tileN + srow) * K + scol;
    const u16* gB1 = Bt + (size_t)(tileN + srow + 64) * K + scol;
    u16* lA0 = sA + w * 512;
    u16* lA1 = sA + 2048 + w * 512;
    u16* lB0 = sB + w * 512;
    u16* lB1 = sB + 2048 + w * 512;

    int aoff[4], boff[4];
#pragma unroll
    for (int m = 0; m < 4; m++) aoff[m] = (wr * 64 + m * 16 + l16) * 32 + lq * 8;
#pragma unroll
    for (int n = 0; n < 4; n++) boff[n] = (wc * 64 + n * 16 + l16) * 32 + lq * 8;

    const int nk = K >> 5;
    for (int kk = 0; kk < nk; ++kk) {
        __syncthreads();
        gload16(gA0, lA0);
        gload16(gA1, lA1);
        gload16(gB0, lB0);
        gload16(gB1, lB1);
        gA0 += 32; gA1 += 32; gB0 += 32; gB1 += 32;
        __syncthreads();
        bf16x8 af[4], bfr[4];
#pragma unroll
        for (int m = 0; m < 4; m++) af[m] = *(const bf16x8*)&sA[aoff[m]];
#pragma unroll
        for (int n = 0; n < 4; n++) bfr[n] = *(const bf16x8*)&sB[boff[n]];
        __builtin_amdgcn_s_setprio(1);
#pragma unroll
        for (int m = 0; m < 4; m++)
#pragma unroll
            for (int n = 0; n < 4; n++)
                acc[m][n] = __builtin_amdgcn_mfma_f32_16x16x32_bf16(af[m], bfr[n], acc[m][n], 0, 0, 0);
        __builtin_amdgcn_s_setprio(0);
    }

    const bool isrope = (tileN >= 1536);
#pragma unroll
    for (int n = 0; n < 4; n++) {
        int col = tileN + wc * 64 + n * 16 + l16;
        float bv = bcat[col];
#pragma unroll
        for (int m = 0; m < 4; m++) {
            int rowb = tileM + wr * 64 + m * 16 + (lq << 2);
#pragma unroll
            for (int r = 0; r < 4; r++) {
                float v = acc[m][n][r] + bv;
                if (!isrope) dcat[(size_t)(rowb + r) * 1536 + col] = v;
                else         krbuf[(size_t)(rowb + r) * 1024 + (col - 1536)] = f2bf(v);
            }
        }
    }
}

// ---------------- RMS norm (row-wise, strided in), fp32 in -> bf16 out --------
template <int C>
__global__ __launch_bounds__(256) void rmsnorm_bf16(
    const float* __restrict__ in, int istride, const float* __restrict__ wgt, u16* __restrict__ out)
{
    const int row = blockIdx.x;
    const int tid = threadIdx.x;
    constexpr int PER = C / 256;
    const float* p = in + (size_t)row * istride;
    float v[PER];
    float ss = 0.f;
#pragma unroll
    for (int i = 0; i < PER; i++) { v[i] = p[tid + i * 256]; ss += v[i] * v[i]; }
#pragma unroll
    for (int o = 32; o; o >>= 1) ss += __shfl_xor(ss, o, 64);
    __shared__ float red[4];
    if ((tid & 63) == 0) red[tid >> 6] = ss;
    __syncthreads();
    float tot = red[0] + red[1] + red[2] + red[3];
    float inv = rsqrtf(tot / (float)C + RMS_EPS);
    u16* q = out + (size_t)row * C;
#pragma unroll
    for (int i = 0; i < PER; i++) {
        int c = tid + i * 256;
        q[c] = f2bf(v[i] * inv * wgt[c]);
    }
}

// ---------------- V transpose: kvbuf[token][h*192+64+d] -> vT[(h*128+d)*4096+token]
__global__ __launch_bounds__(256) void transpose_v(
    const u16* __restrict__ kvbuf, u16* __restrict__ vT)
{
    __shared__ alignas(16) u16 tile[64][72];
    const int tid = threadIdx.x;
    const int t0 = blockIdx.x * 64;
    const int h = blockIdx.y >> 1, dh = blockIdx.y & 1;
    const int trow = tid >> 2, c8 = (tid & 3) * 8;
    const u16* src = kvbuf + (size_t)(t0 + trow) * 3072 + h * 192 + 64 + dh * 64 + c8;
    *(bf16x8*)&tile[trow][c8]      = *(const bf16x8*)src;
    *(bf16x8*)&tile[trow][c8 + 32] = *(const bf16x8*)(src + 32);
    __syncthreads();
    const int drow = tid >> 2, tc8 = (tid & 3) * 8;
    bf16x8 a, b2;
#pragma unroll
    for (int j = 0; j < 8; j++) {
        a[j]  = (short)tile[tc8 + j][drow];
        b2[j] = (short)tile[tc8 + 32 + j][drow];
    }
    u16* dst = vT + (size_t)(h * 128 + dh * 64 + drow) * MROWS + t0 + tc8;
    *(bf16x8*)dst = a;
    *(bf16x8*)(dst + 32) = b2;
}

// ---------------- causal flash attention, 32x32 MFMA, 32 q/wave ----------
// QBLK=128 (4 waves x 32 q), KT=64. Grid (32 bh, 16 y); qt = jj? 15-2*ii : 2*ii
// -> co-resident pairs (qt, 15-qt) give every CU exactly 34 k-tiles.
// Swapped mfma(K,Q): lane = q-column (lane&31); lane and lane^32 hold
// complementary k-row halves -> softmax reduce = in-lane + 1 shfl_xor(32).
// P repacked in-register (16 packs + 8 shfl) -> NO P LDS, no extra barrier.
// LDS = 32 KB (sK 64x128 + sVt 128x64), 2 blocks/CU.
__global__ __launch_bounds__(256, 2) void mla_attn(
    const u16* __restrict__ qbuf,   // (4096, 2048) head-major h*128
    const u16* __restrict__ kvbuf,  // (4096, 3072) per head 192: knope(64) v(128)
    const u16* __restrict__ krbuf,  // (4096, 1024) per head 64
    const u16* __restrict__ vT,     // (h*128+d, 4096 tokens)
    u16* __restrict__ obuf)         // (4096, 2048)
{
    const int bh = blockIdx.x;
    const int y = blockIdx.y;
    const int ii = y & 7, jj = y >> 3;
    const int qt = jj ? (15 - 2 * ii) : (2 * ii);
    const int b = bh >> 4, hh = bh & 15;
    const int tid = threadIdx.x, lane = tid & 63, w = tid >> 6;
    const int l31 = lane & 31, hx = lane >> 5;

    __shared__ alignas(16) u16 sK[64 * 128];
    __shared__ alignas(16) u16 sVt[128 * 64];

    const int rowbase = b * Ss;
    const int q0 = qt * 128;
    const int nkt = 2 * qt + 2;

    const int sr = tid >> 2, sc = (tid & 3) * 32;   // K staging
    const int vd = tid >> 1, vh = (tid & 1) * 32;   // V staging
    const float C1 = 0.12751742f;    // softmax_scale * log2(e)
    const float THRR = 90.5f;        // defer-max threshold (raw score units)

    // Q fragments: lane (q=l31, hx) needs d-chunks (2c + hx), c = 0..7
    bf16x8 qf[8];
    {
        const u16* qp = qbuf + (size_t)(rowbase + q0 + w * 32 + l31) * 2048 + hh * 128;
#pragma unroll
        for (int c = 0; c < 8; c++) qf[c] = *(const bf16x8*)(qp + (2 * c + hx) * 8);
    }
    float mi = -3e38f, li = 0.f;
    f32x16 o[4];
#pragma unroll
    for (int d = 0; d < 4; d++)
#pragma unroll
        for (int i = 0; i < 16; i++) o[d][i] = 0.f;

    bf16x8 kr[4], vr[4];
    {   // prologue: tile 0 -> regs
        const int krow = rowbase + sr;
        const u16* src = (sc < 64)
            ? kvbuf + (size_t)krow * 3072 + hh * 192 + sc
            : krbuf + (size_t)krow * 1024 + hh * 64 + (sc - 64);
#pragma unroll
        for (int j = 0; j < 4; j++) kr[j] = *(const bf16x8*)(src + j * 8);
        const u16* vsrc = vT + (size_t)(hh * 128 + vd) * MROWS + rowbase + vh;
#pragma unroll
        for (int j = 0; j < 4; j++) vr[j] = *(const bf16x8*)(vsrc + j * 8);
    }

#pragma unroll 1
    for (int kt = 0; kt < nkt; ++kt) {
        __syncthreads();
#pragma unroll
        for (int j = 0; j < 4; j++) {
            int byteoff = sr * 256 + (sc + j * 8) * 2;
            *(bf16x8*)((char*)sK + (byteoff ^ ((sr & 7) << 4))) = kr[j];
        }
#pragma unroll
        for (int j = 0; j < 4; j++) {
            int byteoff = vd * 128 + (vh + j * 8) * 2;
            *(bf16x8*)((char*)sVt + (byteoff ^ ((vd & 7) << 4))) = vr[j];
        }
        __syncthreads();
        if (kt + 1 < nkt) {   // prefetch next tile into regs (hides under compute)
            const int krow = rowbase + (kt + 1) * 64 + sr;
            const u16* src = (sc < 64)
                ? kvbuf + (size_t)krow * 3072 + hh * 192 + sc
                : krbuf + (size_t)krow * 1024 + hh * 64 + (sc - 64);
#pragma unroll
            for (int j = 0; j < 4; j++) kr[j] = *(const bf16x8*)(src + j * 8);
            const u16* vsrc = vT + (size_t)(hh * 128 + vd) * MROWS + rowbase + (kt + 1) * 64 + vh;
#pragma unroll
            for (int j = 0; j < 4; j++) vr[j] = *(const bf16x8*)(vsrc + j * 8);
        }

        // wave-dead skip: this wave's q range is [q0+32w, q0+32w+31]
        const bool alive = (kt * 64) <= (q0 + w * 32 + 31);
        if (alive) {
            // QK^T swapped: A=K(32k x 16d), B=Q(16d x 32q) -> D[k][q], q=l31
            f32x16 scf[2];
#pragma unroll
            for (int b2 = 0; b2 < 2; b2++)
#pragma unroll
                for (int i = 0; i < 16; i++) scf[b2][i] = 0.f;
            __builtin_amdgcn_s_setprio(1);
#pragma unroll
            for (int s = 0; s < 8; s++) {
#pragma unroll
                for (int b2 = 0; b2 < 2; b2++) {
                    int krow = b2 * 32 + l31;
                    int kbyte = (krow * 256 + s * 32 + hx * 16) ^ ((l31 & 7) << 4);
                    bf16x8 kf = *(const bf16x8*)((char*)sK + kbyte);
                    scf[b2] = __builtin_amdgcn_mfma_f32_32x32x16_bf16(kf, qf[s], scf[b2], 0, 0, 0);
                }
            }
            __builtin_amdgcn_s_setprio(0);

            // causal mask (only diagonal-adjacent tiles for this wave)
            if (kt * 64 + 63 > q0 + w * 32) {
                const int qg = q0 + w * 32 + l31;
#pragma unroll
                for (int b2 = 0; b2 < 2; b2++)
#pragma unroll
                    for (int rg = 0; rg < 16; rg++) {
                        int kg = kt * 64 + b2 * 32 + (rg & 3) + 8 * (rg >> 2) + 4 * hx;
                        if (kg > qg) scf[b2][rg] = -3e38f;
                    }
            }
            // online softmax: in-lane over 32 vals + partner exchange
            float mx = mi;
#pragma unroll
            for (int b2 = 0; b2 < 2; b2++)
#pragma unroll
                for (int rg = 0; rg < 16; rg++) mx = fmaxf(mx, scf[b2][rg]);
            mx = fmaxf(mx, __shfl_xor(mx, 32, 64));
            if (!__all(mx - mi <= THRR)) {   // T13 defer-max
                float f = exp2_fast((mi - mx) * C1);
                li *= f;
#pragma unroll
                for (int d = 0; d < 4; d++)
#pragma unroll
                    for (int i = 0; i < 16; i++) o[d][i] *= f;
                mi = mx;
            }
            float mc = mi * C1;
            float rs = 0.f;
#pragma unroll
            for (int b2 = 0; b2 < 2; b2++)
#pragma unroll
                for (int rg = 0; rg < 16; rg++) {
                    float pv = exp2_fast(__fmaf_rn(scf[b2][rg], C1, -mc));
                    scf[b2][rg] = pv;
                    rs += pv;
                }
            rs += __shfl_xor(rs, 32, 64);
            li += rs;

            // pack P -> bf16 pairs: pk[b][g] covers rows {8g..8g+3} + 4*hx
            u32 pk[2][4][2];
#pragma unroll
            for (int b2 = 0; b2 < 2; b2++)
#pragma unroll
                for (int g = 0; g < 4; g++) {
                    pk[b2][g][0] = (u32)f2bf(scf[b2][4 * g + 0]) | ((u32)f2bf(scf[b2][4 * g + 1]) << 16);
                    pk[b2][g][1] = (u32)f2bf(scf[b2][4 * g + 2]) | ((u32)f2bf(scf[b2][4 * g + 3]) << 16);
                }

            // PV swapped: A=V^T(32d x 16k), B=P^T(16k x 32q) -> O^T[d][q]
            __builtin_amdgcn_s_setprio(1);
#pragma unroll
            for (int t = 0; t < 4; t++) {
                const int b2 = t >> 1, s = t & 1;
                // exchange with partner (lane^32): send the group partner needs
                u32 send0 = hx ? pk[b2][2 * s][0] : pk[b2][2 * s + 1][0];
                u32 send1 = hx ? pk[b2][2 * s][1] : pk[b2][2 * s + 1][1];
                u32 r0 = (u32)__shfl_xor((int)send0, 32, 64);
                u32 r1 = (u32)__shfl_xor((int)send1, 32, 64);
                union { u32 wd[4]; bf16x8 v; } pu;
                pu.wd[0] = hx ? r0 : pk[b2][2 * s][0];
                pu.wd[1] = hx ? r1 : pk[b2][2 * s][1];
                pu.wd[2] = hx ? pk[b2][2 * s + 1][0] : r0;
                pu.wd[3] = hx ? pk[b2][2 * s + 1][1] : r1;
#pragma unroll
                for (int dblk = 0; dblk < 4; dblk++) {
                    int vrow = dblk * 32 + l31;
                    int vbyte = (vrow * 128 + t * 32 + hx * 16) ^ ((l31 & 7) << 4);
                    bf16x8 vf = *(const bf16x8*)((char*)sVt + vbyte);
                    o[dblk] = __builtin_amdgcn_mfma_f32_32x32x16_bf16(vf, pu.v, o[dblk], 0, 0, 0);
                }
            }
            __builtin_amdgcn_s_setprio(0);
        }
    }
    // epilogue: lane holds O^T[d][q=l31]; d = 32*dblk + 8*rg + 4*hx + a
    float invl = 1.f / li;
    u16* op = obuf + (size_t)(rowbase + q0 + w * 32 + l31) * 2048 + hh * 128;
#pragma unroll
    for (int dblk = 0; dblk < 4; dblk++)
#pragma unroll
        for (int rg = 0; rg < 4; rg++) {
            int d0 = dblk * 32 + rg * 8 + hx * 4;
            ushort4 ov;
            ov.x = f2bf(o[dblk][rg * 4 + 0] * invl);
            ov.y = f2bf(o[dblk][rg * 4 + 1] * invl);
            ov.z = f2bf(o[dblk][rg * 4 + 2] * invl);
            ov.w = f2bf(o[dblk][rg * 4 + 3] * invl);
            *(ushort4*)(op + d0) = ov;
        }
}

// ---------------- launch ----------------
extern "C" void kernel_launch(void* const* d_in, const int* in_sizes, int n_in,
                              void* d_out, int out_size, void* d_ws, size_t ws_size,
                              hipStream_t stream) {
    const float* x        = (const float*)d_in[0];
    const float* q_down_w = (const float*)d_in[1];
    const float* q_down_b = (const float*)d_in[2];
    const float* q_norm_w = (const float*)d_in[3];
    const float* q_up_w   = (const float*)d_in[4];
    const float* q_up_b   = (const float*)d_in[5];
    const float* kv_down_w= (const float*)d_in[6];
    const float* kv_down_b= (const float*)d_in[7];
    const float* kv_norm_w= (const float*)d_in[8];
    const float* kv_up_w  = (const float*)d_in[9];
    const float* kv_up_b  = (const float*)d_in[10];
    const float* k_rope_w = (const float*)d_in[11];
    const float* k_rope_b = (const float*)d_in[12];
    const float* out_w    = (const float*)d_in[13];
    const float* out_b    = (const float*)d_in[14];

    char* ws = (char*)d_ws;
    u16* xbf    = (u16*)(ws + 0);          // 16.78 MB ; later reused as vT
    u16* wcat   = (u16*)(ws + 16777216);   // 10.49 MB (2560x2048 bf16)
    u16* quw    = (u16*)(ws + 27262976);   // 4.19 MB
    u16* kvuw   = (u16*)(ws + 31457280);   // 3.15 MB
    u16* outw   = (u16*)(ws + 34603008);   // 8.39 MB
    float* bcat = (float*)(ws + 42991616); // 10 KB (pad to 16 KB)
    float* dcat = (float*)(ws + 43008000); // 25.17 MB (4096x1536 f32); reused as attnbuf
    u16* cq     = (u16*)(ws + 68173824);   // 8.39 MB
    u16* ckv    = (u16*)(ws + 76562432);   // 4.19 MB
    u16* qbuf   = (u16*)(ws + 80756736);   // 16.78 MB
    u16* kvbuf  = (u16*)(ws + 97533952);   // 25.17 MB
    u16* krbuf  = (u16*)(ws + 122699776);  // 8.39 MB  (end 131,088,384)
    u16* vT     = (u16*)(ws + 0);          // alias xbf (dead after gemm_down)
    u16* attnbuf= (u16*)(ws + 43008000);   // alias dcat (dead after rmsnorms)

    cvt_all<<<20992, 256, 0, stream>>>(
        x, xbf,
        q_down_w,  wcat,
        kv_down_w, wcat + 1024 * 2048,
        k_rope_w,  wcat + 1536 * 2048,
        q_up_w,    quw,
        kv_up_w,   kvuw,
        out_w,     outw);
    build_bcat<<<10, 256, 0, stream>>>(q_down_b, kv_down_b, k_rope_b, bcat);

    // fused down projections: x @ [q_down|kv_down|k_rope]^T
    gemm_down<<<dim3(20, 32), 256, 0, stream>>>(xbf, wcat, bcat, dcat, krbuf);
    rmsnorm_bf16<1024><<<MROWS, 256, 0, stream>>>(dcat, 1536, q_norm_w, cq);
    rmsnorm_bf16<512><<<MROWS, 256, 0, stream>>>(dcat + 1024, 1536, kv_norm_w, ckv);
    // up projections
    gemm_bt<u16><<<dim3(16, 32), 256, 0, stream>>>(cq, quw, q_up_b, qbuf, MROWS, 2048, 1024);
    gemm_bt<u16><<<dim3(24, 32), 256, 0, stream>>>(ckv, kvuw, kv_up_b, kvbuf, MROWS, 3072, 512);
    // V transpose (vT aliases xbf; xbf dead after gemm_down)
    transpose_v<<<dim3(64, 32), 256, 0, stream>>>(kvbuf, vT);
    // attention: 512 blocks (32 bh x 16 qt balanced-paired), 2 blocks/CU
    mla_attn<<<dim3(32, 16), 256, 0, stream>>>(qbuf, kvbuf, krbuf, vT, attnbuf);
    // output projection
    gemm_bt<float><<<dim3(16, 32), 256, 0, stream>>>(attnbuf, outw, out_b, (float*)d_out, MROWS, 2048, 2048);
}